// Round 2
// baseline (140.205 us; speedup 1.0000x reference)
//
#include <hip/hip_runtime.h>
#include <hip/hip_bf16.h>
#include <cstddef>

#define BB 4
#define CC 64
#define UU 5
#define VV 5
#define HH 64
#define WW 64
#define NIJ (69*69)   // 4761

__device__ __forceinline__ float rdlane(float v, int l) {
    return __uint_as_float((unsigned)__builtin_amdgcn_readlane((int)__float_as_uint(v), l));
}

// ---------------------------------------------------------------------------
// K1: one pass over x -> 4 means, written CHANNEL-FIRST fully coalesced.
//   m_hw[bc][h*64+w]  (scaled 1/25)
//   m_uh[bc][u][h]    (scaled 1/320)
//   m_vw[bc][v][w]    (scaled 1/320)
//   m_uv[bc][u][v]    (scaled 1/4096)
// grid: B*C = 256 blocks, 512 threads. ONE barrier total, no per-tile sync.
// ---------------------------------------------------------------------------
__global__ __launch_bounds__(512) void k1_means(const float* __restrict__ x,
        float* __restrict__ m_hw, float* __restrict__ m_uh,
        float* __restrict__ m_vw, float* __restrict__ m_uv) {
    const int bc = blockIdx.x;
    const float4* xb4 = (const float4*)(x + (size_t)bc * (UU*VV*HH*WW));
    const int t    = threadIdx.x;     // 0..511
    const int wave = t >> 6;
    const int lane = t & 63;

    __shared__ float4 vw_lds[8][5][16];   // per-wave vw partials
    __shared__ float  uv_lds[8][25];      // per-wave uv partials

    float4 hw0 = make_float4(0.f,0.f,0.f,0.f);
    float4 hw1 = make_float4(0.f,0.f,0.f,0.f);
    float4 vwacc[5];
    #pragma unroll
    for (int v = 0; v < 5; ++v) vwacc[v] = make_float4(0.f,0.f,0.f,0.f);

    #pragma unroll 1
    for (int u = 0; u < 5; ++u) {
        // issue all 10 tile loads for this u up front (burst -> MLP)
        float4 A[5], B[5];
        #pragma unroll
        for (int v = 0; v < 5; ++v) {
            const float4* xt = xb4 + (size_t)(u*5 + v) * 1024;
            A[v] = xt[t];
            B[v] = xt[512 + t];
        }
        float uh0 = 0.f, uh1 = 0.f;
        #pragma unroll
        for (int v = 0; v < 5; ++v) {
            float4 a = A[v], b = B[v];
            // hw accumulation (thread owns quads t and 512+t)
            hw0.x += a.x; hw0.y += a.y; hw0.z += a.z; hw0.w += a.w;
            hw1.x += b.x; hw1.y += b.y; hw1.z += b.z; hw1.w += b.w;
            // row sums over w: 16 lanes (same t>>4) cover one h-row
            float r0 = (a.x + a.y) + (a.z + a.w);
            float r1 = (b.x + b.y) + (b.z + b.w);
            r0 += __shfl_xor(r0, 1); r0 += __shfl_xor(r0, 2);
            r0 += __shfl_xor(r0, 4); r0 += __shfl_xor(r0, 8);
            r1 += __shfl_xor(r1, 1); r1 += __shfl_xor(r1, 2);
            r1 += __shfl_xor(r1, 4); r1 += __shfl_xor(r1, 8);
            uh0 += r0; uh1 += r1;
            // column partial for this thread's two rows
            float4 cs;
            cs.x = a.x + b.x; cs.y = a.y + b.y; cs.z = a.z + b.z; cs.w = a.w + b.w;
            cs.x += __shfl_xor(cs.x, 16); cs.y += __shfl_xor(cs.y, 16);
            cs.z += __shfl_xor(cs.z, 16); cs.w += __shfl_xor(cs.w, 16);
            cs.x += __shfl_xor(cs.x, 32); cs.y += __shfl_xor(cs.y, 32);
            cs.z += __shfl_xor(cs.z, 32); cs.w += __shfl_xor(cs.w, 32);
            vwacc[v].x += cs.x; vwacc[v].y += cs.y;
            vwacc[v].z += cs.z; vwacc[v].w += cs.w;
            // tile total (this wave's 8 rows)
            float s = (cs.x + cs.y) + (cs.z + cs.w);
            s += __shfl_xor(s, 1); s += __shfl_xor(s, 2);
            s += __shfl_xor(s, 4); s += __shfl_xor(s, 8);
            if (lane == 0) uv_lds[wave][u*5 + v] = s;
        }
        // uh final for this u (sum over v,w done)
        if ((t & 15) == 0) {
            const int hb = t >> 4;    // 0..31
            m_uh[(size_t)bc*320 + u*64 + hb]      = uh0 * (1.f/320.f);
            m_uh[(size_t)bc*320 + u*64 + 32 + hb] = uh1 * (1.f/320.f);
        }
    }

    #pragma unroll
    for (int v = 0; v < 5; ++v)
        if (lane < 16) vw_lds[wave][v][lane] = vwacc[v];
    __syncthreads();

    // hw out: contiguous 16KB per block
    float4* mh4 = (float4*)m_hw + (size_t)bc * 1024;
    const float s25 = 1.f/25.f;
    float4 o0, o1;
    o0.x = hw0.x*s25; o0.y = hw0.y*s25; o0.z = hw0.z*s25; o0.w = hw0.w*s25;
    o1.x = hw1.x*s25; o1.y = hw1.y*s25; o1.z = hw1.z*s25; o1.w = hw1.w*s25;
    mh4[t] = o0;
    mh4[512 + t] = o1;

    if (t < 80) {   // vw: cross-wave reduce
        const int v = t >> 4, wq = t & 15;
        float4 s = vw_lds[0][v][wq];
        #pragma unroll
        for (int w8 = 1; w8 < 8; ++w8) {
            float4 p = vw_lds[w8][v][wq];
            s.x += p.x; s.y += p.y; s.z += p.z; s.w += p.w;
        }
        const float sc = 1.f/320.f;
        s.x *= sc; s.y *= sc; s.z *= sc; s.w *= sc;
        ((float4*)m_vw)[(size_t)bc*80 + t] = s;
    }
    if (t < 25) {   // uv: cross-wave reduce
        float s = 0.f;
        #pragma unroll
        for (int w8 = 0; w8 < 8; ++w8) s += uv_lds[w8][t];
        m_uv[(size_t)bc*25 + t] = s * (1.f/4096.f);
    }
}

// ---------------------------------------------------------------------------
// K1b: transpose channel-first means -> channel-last grid_t[b][ij][c]
// blocks 0..255: (b,h) top rows; blocks 256..275: (b,v) bottom rows. 256 thr.
// ---------------------------------------------------------------------------
__global__ __launch_bounds__(256) void k1b_assemble(
        const float* __restrict__ m_hw, const float* __restrict__ m_uh,
        const float* __restrict__ m_vw, const float* __restrict__ m_uv,
        float* __restrict__ grid_t) {
    __shared__ float tile[64][68];
    const int t = threadIdx.x;
    const int c = t >> 2, qsel = t & 3;
    const int blk = blockIdx.x;
    const bool top = blk < 256;
    const int b = top ? (blk >> 6) : (blk - 256) / 5;
    const int r = top ? (blk & 63) : (blk - 256) % 5;   // h (top) or v (bot)

    const float4* src4 = top
        ? (const float4*)m_hw + ((size_t)(b*64 + c) * 1024 + r*16)
        : (const float4*)m_vw + ((size_t)(b*64 + c) * 80  + r*16);
    #pragma unroll
    for (int j = 0; j < 4; ++j) {
        float4 v = src4[4*j + qsel];
        const int w = (4*j + qsel) * 4;
        tile[w+0][c] = v.x; tile[w+1][c] = v.y;
        tile[w+2][c] = v.z; tile[w+3][c] = v.w;
    }
    __syncthreads();

    const int i = top ? r : (64 + r);
    float4* dst4 = (float4*)grid_t + ((size_t)b*NIJ + i*69) * 16;
    #pragma unroll
    for (int k = 0; k < 4; ++k) {
        const int oidx = k*256 + t;
        const int w = oidx >> 4, cq = (oidx & 15) * 4;
        float4 v;
        v.x = tile[w][cq]; v.y = tile[w][cq+1];
        v.z = tile[w][cq+2]; v.w = tile[w][cq+3];
        dst4[oidx] = v;
    }
    // border columns j = 64..68
    for (int idx = t; idx < 320; idx += 256) {
        const int u = idx >> 6, cc = idx & 63;
        float val = top ? m_uh[(size_t)(b*64 + cc)*320 + u*64 + r]
                        : m_uv[(size_t)(b*64 + cc)*25  + u*5  + r];
        grid_t[((size_t)b*NIJ + i*69 + 64 + u)*64 + cc] = val;
    }
}

// ---------------------------------------------------------------------------
// K2: per-position MLP (w1/silu/w2) + region conv (fw0..3), lane = out channel
// grid: B*69 = 276 blocks (one grid row each), 512 threads = 8 waves
// ---------------------------------------------------------------------------
#define LOADROW(dst, src)                                              \
    { _Pragma("unroll")                                                \
      for (int q = 0; q < 16; ++q) {                                   \
          float4 t4 = ((const float4*)(src))[lane*16 + q];             \
          dst[4*q+0] = t4.x; dst[4*q+1] = t4.y;                        \
          dst[4*q+2] = t4.z; dst[4*q+3] = t4.w;                        \
      } }

#define DOT64(res, wr, src)                                            \
    float res;                                                         \
    { float _a0=0.f,_a1=0.f,_a2=0.f,_a3=0.f;                           \
      _Pragma("unroll")                                                \
      for (int cc2 = 0; cc2 < 64; cc2 += 4) {                          \
          _a0 = fmaf(wr[cc2+0], rdlane(src, cc2+0), _a0);              \
          _a1 = fmaf(wr[cc2+1], rdlane(src, cc2+1), _a1);              \
          _a2 = fmaf(wr[cc2+2], rdlane(src, cc2+2), _a2);              \
          _a3 = fmaf(wr[cc2+3], rdlane(src, cc2+3), _a3);              \
      }                                                                \
      res = (_a0 + _a1) + (_a2 + _a3); }

#define MLP_BODY(J)                                                    \
    {                                                                  \
        const int jj = (J);                                            \
        float v = gtb[(size_t)(i*69 + jj) * CC + lane];                \
        DOT64(d1, w1r, v);                                             \
        float acc1 = d1 + b1v;                                         \
        float ya = acc1 / (1.f + __expf(-acc1));                       \
        DOT64(d2, w2r, ya);                                            \
        float acc2 = d2 + b2v;                                         \
        DOT64(d3, fr, acc2);                                           \
        sp[(size_t)(jj - jbase) * sstr] = d3 + fbv;                    \
    }

__global__ __launch_bounds__(512) void k2_mlp(
        const float* __restrict__ grid_t,
        const float* __restrict__ w1, const float* __restrict__ b1,
        const float* __restrict__ w2, const float* __restrict__ b2,
        const float* __restrict__ fw0, const float* __restrict__ fb0,
        const float* __restrict__ fw1, const float* __restrict__ fb1,
        const float* __restrict__ fw2, const float* __restrict__ fb2,
        const float* __restrict__ fw3, const float* __restrict__ fb3,
        float* __restrict__ mod_hw, float* __restrict__ mod_uh,
        float* __restrict__ mod_vw, float* __restrict__ mod_uv) {
    const int row  = blockIdx.x;          // 0..275
    const int b    = row / 69;
    const int i    = row % 69;
    const int wave = threadIdx.x >> 6;
    const int lane = threadIdx.x & 63;

    const int j0 = wave * 9;
    const int j1 = min(69, j0 + 9);
    const bool top = (i < 64);

    const float* fwA = top ? fw0 : fw3;
    const float* fbA = top ? fb0 : fb3;
    const float* fwB = top ? fw2 : fw1;
    const float* fbB = top ? fb2 : fb1;

    float w1r[64], w2r[64], fr[64];
    LOADROW(w1r, w1);
    LOADROW(w2r, w2);
    const float b1v = b1[lane];
    const float b2v = b2[lane];

    const float* gtb = grid_t + (size_t)b * NIJ * CC;
    const int cbl = b * CC + lane;        // output channel index with batch

    const int jm = min(j1, 64);
    if (j0 < jm) {                        // region A: j < 64
        LOADROW(fr, fwA);
        const float fbv = fbA[lane];
        float* sp; int sstr; const int jbase = 0;
        if (top) { sp = mod_hw + ((size_t)cbl*64 + i)*64;          sstr = 1; }  // [c][h=i][w=j]
        else     { sp = mod_vw + (size_t)cbl*320 + (i-64)*64;      sstr = 1; }  // [c][v=i-64][w=j]
        for (int j = j0; j < jm; ++j) MLP_BODY(j)
    }
    if (j1 > 64) {                        // region B: j >= 64
        LOADROW(fr, fwB);
        const float fbv = fbB[lane];
        float* sp; int sstr; const int jbase = 64;
        if (top) { sp = mod_uh + (size_t)cbl*320 + i;              sstr = 64; } // [c][u=j-64][h=i]
        else     { sp = mod_uv + (size_t)cbl*25 + (i-64);          sstr = 5;  } // [c][u=j-64][v=i-64]
        const int jb = max(j0, 64);
        for (int j = jb; j < j1; ++j) MLP_BODY(j)
    }
}

// ---------------------------------------------------------------------------
// K3: out = x * (mod_hw + mod_uv + mod_uh + mod_vw)
// grid: B*C*U*V = 1600 blocks, 256 threads, 4 float4 per thread
// ---------------------------------------------------------------------------
__global__ __launch_bounds__(256) void k3_apply(
        const float* __restrict__ x,
        const float* __restrict__ mod_hw, const float* __restrict__ mod_uh,
        const float* __restrict__ mod_vw, const float* __restrict__ mod_uv,
        float* __restrict__ out) {
    const int blk = blockIdx.x;           // (b*C + c)*25 + u*5 + v
    const int vv  = blk % 5;
    const int u   = (blk / 5) % 5;
    const int bc  = blk / 25;

    const size_t xoff = ((size_t)bc * 25 + u*5 + vv) * (HH*WW);
    const float4* x4 = (const float4*)(x + xoff);
    float4* o4 = (float4*)(out + xoff);
    const float4* mhw4 = (const float4*)(mod_hw + (size_t)bc * (HH*WW));

    __shared__ float  uh_s[HH];
    __shared__ float4 vw_s4[16];

    const int t = threadIdx.x;
    if (t < 64) uh_s[t] = mod_uh[(size_t)bc*320 + u*64 + t];
    else if (t < 128) {
        const int w = t - 64;
        ((float*)vw_s4)[w] = mod_vw[(size_t)bc*320 + vv*64 + w];
    }
    const float muv = mod_uv[(size_t)bc*25 + u*5 + vv];
    __syncthreads();

    #pragma unroll
    for (int k = 0; k < 4; ++k) {
        const int f = k*256 + t;          // 0..1023
        const int h = f >> 4;
        float4 xv = x4[f];
        float4 mh = mhw4[f];
        float4 vw = vw_s4[f & 15];
        const float s = muv + uh_s[h];
        float4 r;
        r.x = xv.x * (mh.x + vw.x + s);
        r.y = xv.y * (mh.y + vw.y + s);
        r.z = xv.z * (mh.z + vw.z + s);
        r.w = xv.w * (mh.w + vw.w + s);
        o4[f] = r;
    }
}

// ---------------------------------------------------------------------------
extern "C" void kernel_launch(void* const* d_in, const int* in_sizes, int n_in,
                              void* d_out, int out_size, void* d_ws, size_t ws_size,
                              hipStream_t stream) {
    const float* x   = (const float*)d_in[0];
    const float* w1  = (const float*)d_in[1];
    const float* b1  = (const float*)d_in[2];
    const float* w2  = (const float*)d_in[3];
    const float* b2  = (const float*)d_in[4];
    const float* fw0 = (const float*)d_in[5];
    const float* fb0 = (const float*)d_in[6];
    const float* fw1 = (const float*)d_in[7];
    const float* fb1 = (const float*)d_in[8];
    const float* fw2 = (const float*)d_in[9];
    const float* fb2 = (const float*)d_in[10];
    const float* fw3 = (const float*)d_in[11];
    const float* fb3 = (const float*)d_in[12];

    float* ws = (float*)d_ws;
    float* grid_t = ws;                        // 4*4761*64      = 1,218,816
    float* m_hw   = ws + 1218816;              // 256*4096       = 1,048,576
    float* m_uh   = m_hw + 1048576;            // 256*320        =    81,920
    float* m_vw   = m_uh + 81920;              // 256*320        =    81,920
    float* m_uv   = m_vw + 81920;              // 256*25         =     6,400
    // after k1b, m_* are dead -> reuse the same region for mod_* (same sizes)
    float* mod_hw = m_hw;
    float* mod_uh = m_uh;
    float* mod_vw = m_vw;
    float* mod_uv = m_uv;

    k1_means<<<BB*CC, 512, 0, stream>>>(x, m_hw, m_uh, m_vw, m_uv);
    k1b_assemble<<<BB*CC + BB*VV, 256, 0, stream>>>(m_hw, m_uh, m_vw, m_uv, grid_t);
    k2_mlp<<<BB*69, 512, 0, stream>>>(grid_t, w1, b1, w2, b2,
                                      fw0, fb0, fw1, fb1, fw2, fb2, fw3, fb3,
                                      mod_hw, mod_uh, mod_vw, mod_uv);
    k3_apply<<<BB*CC*UU*VV, 256, 0, stream>>>(x, mod_hw, mod_uh, mod_vw, mod_uv,
                                              (float*)d_out);
}

// Round 3
// 111.531 us; speedup vs baseline: 1.2571x; 1.2571x over previous
//
#include <hip/hip_runtime.h>
#include <hip/hip_bf16.h>
#include <cstddef>

#define BB 4
#define CC 64
#define UU 5
#define VV 5
#define HH 64
#define WW 64
#define NIJ (69*69)   // 4761

__device__ __forceinline__ float rdlane(float v, int l) {
    return __uint_as_float((unsigned)__builtin_amdgcn_readlane((int)__float_as_uint(v), l));
}

// ---------------------------------------------------------------------------
// K1: one pass over x -> 4 means, written CHANNEL-FIRST fully coalesced.
// grid: B*C = 256 blocks, 512 threads. ONE barrier total.
// ---------------------------------------------------------------------------
__global__ __launch_bounds__(512) void k1_means(const float* __restrict__ x,
        float* __restrict__ m_hw, float* __restrict__ m_uh,
        float* __restrict__ m_vw, float* __restrict__ m_uv) {
    const int bc = blockIdx.x;
    const float4* xb4 = (const float4*)(x + (size_t)bc * (UU*VV*HH*WW));
    const int t    = threadIdx.x;     // 0..511
    const int wave = t >> 6;
    const int lane = t & 63;

    __shared__ float4 vw_lds[8][5][16];   // per-wave vw partials
    __shared__ float  uv_lds[8][25];      // per-wave uv partials

    float4 hw0 = make_float4(0.f,0.f,0.f,0.f);
    float4 hw1 = make_float4(0.f,0.f,0.f,0.f);
    float4 vwacc[5];
    #pragma unroll
    for (int v = 0; v < 5; ++v) vwacc[v] = make_float4(0.f,0.f,0.f,0.f);

    #pragma unroll 1
    for (int u = 0; u < 5; ++u) {
        float4 A[5], B[5];
        #pragma unroll
        for (int v = 0; v < 5; ++v) {
            const float4* xt = xb4 + (size_t)(u*5 + v) * 1024;
            A[v] = xt[t];
            B[v] = xt[512 + t];
        }
        float uh0 = 0.f, uh1 = 0.f;
        #pragma unroll
        for (int v = 0; v < 5; ++v) {
            float4 a = A[v], b = B[v];
            hw0.x += a.x; hw0.y += a.y; hw0.z += a.z; hw0.w += a.w;
            hw1.x += b.x; hw1.y += b.y; hw1.z += b.z; hw1.w += b.w;
            float r0 = (a.x + a.y) + (a.z + a.w);
            float r1 = (b.x + b.y) + (b.z + b.w);
            r0 += __shfl_xor(r0, 1); r0 += __shfl_xor(r0, 2);
            r0 += __shfl_xor(r0, 4); r0 += __shfl_xor(r0, 8);
            r1 += __shfl_xor(r1, 1); r1 += __shfl_xor(r1, 2);
            r1 += __shfl_xor(r1, 4); r1 += __shfl_xor(r1, 8);
            uh0 += r0; uh1 += r1;
            float4 cs;
            cs.x = a.x + b.x; cs.y = a.y + b.y; cs.z = a.z + b.z; cs.w = a.w + b.w;
            cs.x += __shfl_xor(cs.x, 16); cs.y += __shfl_xor(cs.y, 16);
            cs.z += __shfl_xor(cs.z, 16); cs.w += __shfl_xor(cs.w, 16);
            cs.x += __shfl_xor(cs.x, 32); cs.y += __shfl_xor(cs.y, 32);
            cs.z += __shfl_xor(cs.z, 32); cs.w += __shfl_xor(cs.w, 32);
            vwacc[v].x += cs.x; vwacc[v].y += cs.y;
            vwacc[v].z += cs.z; vwacc[v].w += cs.w;
            float s = (cs.x + cs.y) + (cs.z + cs.w);
            s += __shfl_xor(s, 1); s += __shfl_xor(s, 2);
            s += __shfl_xor(s, 4); s += __shfl_xor(s, 8);
            if (lane == 0) uv_lds[wave][u*5 + v] = s;
        }
        if ((t & 15) == 0) {
            const int hb = t >> 4;    // 0..31
            m_uh[(size_t)bc*320 + u*64 + hb]      = uh0 * (1.f/320.f);
            m_uh[(size_t)bc*320 + u*64 + 32 + hb] = uh1 * (1.f/320.f);
        }
    }

    #pragma unroll
    for (int v = 0; v < 5; ++v)
        if (lane < 16) vw_lds[wave][v][lane] = vwacc[v];
    __syncthreads();

    float4* mh4 = (float4*)m_hw + (size_t)bc * 1024;
    const float s25 = 1.f/25.f;
    float4 o0, o1;
    o0.x = hw0.x*s25; o0.y = hw0.y*s25; o0.z = hw0.z*s25; o0.w = hw0.w*s25;
    o1.x = hw1.x*s25; o1.y = hw1.y*s25; o1.z = hw1.z*s25; o1.w = hw1.w*s25;
    mh4[t] = o0;
    mh4[512 + t] = o1;

    if (t < 80) {
        const int v = t >> 4, wq = t & 15;
        float4 s = vw_lds[0][v][wq];
        #pragma unroll
        for (int w8 = 1; w8 < 8; ++w8) {
            float4 p = vw_lds[w8][v][wq];
            s.x += p.x; s.y += p.y; s.z += p.z; s.w += p.w;
        }
        const float sc = 1.f/320.f;
        s.x *= sc; s.y *= sc; s.z *= sc; s.w *= sc;
        ((float4*)m_vw)[(size_t)bc*80 + t] = s;
    }
    if (t < 25) {
        float s = 0.f;
        #pragma unroll
        for (int w8 = 0; w8 < 8; ++w8) s += uv_lds[w8][t];
        m_uv[(size_t)bc*25 + t] = s * (1.f/4096.f);
    }
}

// ---------------------------------------------------------------------------
// K1b: transpose channel-first means -> channel-last grid_t[b][ij][c]
// ---------------------------------------------------------------------------
__global__ __launch_bounds__(256) void k1b_assemble(
        const float* __restrict__ m_hw, const float* __restrict__ m_uh,
        const float* __restrict__ m_vw, const float* __restrict__ m_uv,
        float* __restrict__ grid_t) {
    __shared__ float tile[64][68];
    const int t = threadIdx.x;
    const int c = t >> 2, qsel = t & 3;
    const int blk = blockIdx.x;
    const bool top = blk < 256;
    const int b = top ? (blk >> 6) : (blk - 256) / 5;
    const int r = top ? (blk & 63) : (blk - 256) % 5;   // h (top) or v (bot)

    const float4* src4 = top
        ? (const float4*)m_hw + ((size_t)(b*64 + c) * 1024 + r*16)
        : (const float4*)m_vw + ((size_t)(b*64 + c) * 80  + r*16);
    #pragma unroll
    for (int j = 0; j < 4; ++j) {
        float4 v = src4[4*j + qsel];
        const int w = (4*j + qsel) * 4;
        tile[w+0][c] = v.x; tile[w+1][c] = v.y;
        tile[w+2][c] = v.z; tile[w+3][c] = v.w;
    }
    __syncthreads();

    const int i = top ? r : (64 + r);
    float4* dst4 = (float4*)grid_t + ((size_t)b*NIJ + i*69) * 16;
    #pragma unroll
    for (int k = 0; k < 4; ++k) {
        const int oidx = k*256 + t;
        const int w = oidx >> 4, cq = (oidx & 15) * 4;
        float4 v;
        v.x = tile[w][cq]; v.y = tile[w][cq+1];
        v.z = tile[w][cq+2]; v.w = tile[w][cq+3];
        dst4[oidx] = v;
    }
    for (int idx = t; idx < 320; idx += 256) {
        const int u = idx >> 6, cc = idx & 63;
        float val = top ? m_uh[(size_t)(b*64 + cc)*320 + u*64 + r]
                        : m_uv[(size_t)(b*64 + cc)*25  + u*5  + r];
        grid_t[((size_t)b*NIJ + i*69 + 64 + u)*64 + cc] = val;
    }
}

// ---------------------------------------------------------------------------
// K2: per-position MLP + region conv. 256 threads = 4 waves x 18 columns.
// __launch_bounds__(256, 1): allow up to 512 VGPR so the 192-float weight
// arrays stay in registers (R2's 512-thr version capped at 128 VGPR and
// spilled ~117MB of scratch traffic -> 83-105us).
// ---------------------------------------------------------------------------
#define LOADROW(dst, src)                                              \
    { _Pragma("unroll")                                                \
      for (int q = 0; q < 16; ++q) {                                   \
          float4 t4 = ((const float4*)(src))[lane*16 + q];             \
          dst[4*q+0] = t4.x; dst[4*q+1] = t4.y;                        \
          dst[4*q+2] = t4.z; dst[4*q+3] = t4.w;                        \
      } }

#define DOT64(res, wr, src)                                            \
    float res;                                                         \
    { float _a0=0.f,_a1=0.f,_a2=0.f,_a3=0.f;                           \
      _Pragma("unroll")                                                \
      for (int cc2 = 0; cc2 < 64; cc2 += 4) {                          \
          _a0 = fmaf(wr[cc2+0], rdlane(src, cc2+0), _a0);              \
          _a1 = fmaf(wr[cc2+1], rdlane(src, cc2+1), _a1);              \
          _a2 = fmaf(wr[cc2+2], rdlane(src, cc2+2), _a2);              \
          _a3 = fmaf(wr[cc2+3], rdlane(src, cc2+3), _a3);              \
      }                                                                \
      res = (_a0 + _a1) + (_a2 + _a3); }

#define MLP_BODY(J)                                                    \
    {                                                                  \
        const int jj = (J);                                            \
        float v = gtb[(size_t)(i*69 + jj) * CC + lane];                \
        DOT64(d1, w1r, v);                                             \
        float acc1 = d1 + b1v;                                         \
        float ya = acc1 / (1.f + __expf(-acc1));                       \
        DOT64(d2, w2r, ya);                                            \
        float acc2 = d2 + b2v;                                         \
        DOT64(d3, fr, acc2);                                           \
        sp[(size_t)(jj - jbase) * sstr] = d3 + fbv;                    \
    }

__global__ __launch_bounds__(256, 1) void k2_mlp(
        const float* __restrict__ grid_t,
        const float* __restrict__ w1, const float* __restrict__ b1,
        const float* __restrict__ w2, const float* __restrict__ b2,
        const float* __restrict__ fw0, const float* __restrict__ fb0,
        const float* __restrict__ fw1, const float* __restrict__ fb1,
        const float* __restrict__ fw2, const float* __restrict__ fb2,
        const float* __restrict__ fw3, const float* __restrict__ fb3,
        float* __restrict__ mod_hw, float* __restrict__ mod_uh,
        float* __restrict__ mod_vw, float* __restrict__ mod_uv) {
    const int row  = blockIdx.x;          // 0..275
    const int b    = row / 69;
    const int i    = row % 69;
    const int wave = threadIdx.x >> 6;
    const int lane = threadIdx.x & 63;

    const int j0 = wave * 18;
    const int j1 = min(69, j0 + 18);
    const bool top = (i < 64);

    const float* fwA = top ? fw0 : fw3;
    const float* fbA = top ? fb0 : fb3;
    const float* fwB = top ? fw2 : fw1;
    const float* fbB = top ? fb2 : fb1;

    float w1r[64], w2r[64], fr[64];
    LOADROW(w1r, w1);
    LOADROW(w2r, w2);
    const float b1v = b1[lane];
    const float b2v = b2[lane];

    const float* gtb = grid_t + (size_t)b * NIJ * CC;
    const int cbl = b * CC + lane;        // output channel index with batch

    const int jm = min(j1, 64);
    if (j0 < jm) {                        // region A: j < 64
        LOADROW(fr, fwA);
        const float fbv = fbA[lane];
        float* sp; int sstr; const int jbase = 0;
        if (top) { sp = mod_hw + ((size_t)cbl*64 + i)*64;          sstr = 1; }  // [c][h=i][w=j]
        else     { sp = mod_vw + (size_t)cbl*320 + (i-64)*64;      sstr = 1; }  // [c][v=i-64][w=j]
        for (int j = j0; j < jm; ++j) MLP_BODY(j)
    }
    if (j1 > 64) {                        // region B: j >= 64
        LOADROW(fr, fwB);
        const float fbv = fbB[lane];
        float* sp; int sstr; const int jbase = 64;
        if (top) { sp = mod_uh + (size_t)cbl*320 + i;              sstr = 64; } // [c][u=j-64][h=i]
        else     { sp = mod_uv + (size_t)cbl*25 + (i-64);          sstr = 5;  } // [c][u=j-64][v=i-64]
        const int jb = max(j0, 64);
        for (int j = jb; j < j1; ++j) MLP_BODY(j)
    }
}

// ---------------------------------------------------------------------------
// K3: out = x * (mod_hw + mod_uv + mod_uh + mod_vw)
// grid: B*C*U*V = 1600 blocks, 256 threads, 4 float4 per thread
// ---------------------------------------------------------------------------
__global__ __launch_bounds__(256) void k3_apply(
        const float* __restrict__ x,
        const float* __restrict__ mod_hw, const float* __restrict__ mod_uh,
        const float* __restrict__ mod_vw, const float* __restrict__ mod_uv,
        float* __restrict__ out) {
    const int blk = blockIdx.x;           // (b*C + c)*25 + u*5 + v
    const int vv  = blk % 5;
    const int u   = (blk / 5) % 5;
    const int bc  = blk / 25;

    const size_t xoff = ((size_t)bc * 25 + u*5 + vv) * (HH*WW);
    const float4* x4 = (const float4*)(x + xoff);
    float4* o4 = (float4*)(out + xoff);
    const float4* mhw4 = (const float4*)(mod_hw + (size_t)bc * (HH*WW));

    __shared__ float  uh_s[HH];
    __shared__ float4 vw_s4[16];

    const int t = threadIdx.x;
    if (t < 64) uh_s[t] = mod_uh[(size_t)bc*320 + u*64 + t];
    else if (t < 128) {
        const int w = t - 64;
        ((float*)vw_s4)[w] = mod_vw[(size_t)bc*320 + vv*64 + w];
    }
    const float muv = mod_uv[(size_t)bc*25 + u*5 + vv];
    __syncthreads();

    #pragma unroll
    for (int k = 0; k < 4; ++k) {
        const int f = k*256 + t;          // 0..1023
        const int h = f >> 4;
        float4 xv = x4[f];
        float4 mh = mhw4[f];
        float4 vw = vw_s4[f & 15];
        const float s = muv + uh_s[h];
        float4 r;
        r.x = xv.x * (mh.x + vw.x + s);
        r.y = xv.y * (mh.y + vw.y + s);
        r.z = xv.z * (mh.z + vw.z + s);
        r.w = xv.w * (mh.w + vw.w + s);
        o4[f] = r;
    }
}

// ---------------------------------------------------------------------------
extern "C" void kernel_launch(void* const* d_in, const int* in_sizes, int n_in,
                              void* d_out, int out_size, void* d_ws, size_t ws_size,
                              hipStream_t stream) {
    const float* x   = (const float*)d_in[0];
    const float* w1  = (const float*)d_in[1];
    const float* b1  = (const float*)d_in[2];
    const float* w2  = (const float*)d_in[3];
    const float* b2  = (const float*)d_in[4];
    const float* fw0 = (const float*)d_in[5];
    const float* fb0 = (const float*)d_in[6];
    const float* fw1 = (const float*)d_in[7];
    const float* fb1 = (const float*)d_in[8];
    const float* fw2 = (const float*)d_in[9];
    const float* fb2 = (const float*)d_in[10];
    const float* fw3 = (const float*)d_in[11];
    const float* fb3 = (const float*)d_in[12];

    float* ws = (float*)d_ws;
    float* grid_t = ws;                        // 4*4761*64      = 1,218,816
    float* m_hw   = ws + 1218816;              // 256*4096       = 1,048,576
    float* m_uh   = m_hw + 1048576;            // 256*320        =    81,920
    float* m_vw   = m_uh + 81920;              // 256*320        =    81,920
    float* m_uv   = m_vw + 81920;              // 256*25         =     6,400
    float* mod_hw = m_hw;
    float* mod_uh = m_uh;
    float* mod_vw = m_vw;
    float* mod_uv = m_uv;

    k1_means<<<BB*CC, 512, 0, stream>>>(x, m_hw, m_uh, m_vw, m_uv);
    k1b_assemble<<<BB*CC + BB*VV, 256, 0, stream>>>(m_hw, m_uh, m_vw, m_uv, grid_t);
    k2_mlp<<<BB*69, 256, 0, stream>>>(grid_t, w1, b1, w2, b2,
                                      fw0, fb0, fw1, fb1, fw2, fb2, fw3, fb3,
                                      mod_hw, mod_uh, mod_vw, mod_uv);
    k3_apply<<<BB*CC*UU*VV, 256, 0, stream>>>(x, mod_hw, mod_uh, mod_vw, mod_uv,
                                              (float*)d_out);
}